// Round 11
// baseline (66.342 us; speedup 1.0000x reference)
//
#include <hip/hip_runtime.h>
#include <hip/hip_fp16.h>
#include <math.h>

// Problem constants (match reference exactly)
#define BROWS 1024
#define NPTS  32768
#define MPTS  16384          // complex FFT size via real-packing trick
#define NTHR  512            // 8 waves
#define MIN_IDX 1092         // argmin |f - 40/60|, f[k]=k*10/16384 (exact fp32 grid)
#define MAX_IDX 6827         // argmin |f - 250/60|
#define DENOMF  5732.0f      // MAX_IDX - MIN_IDX - 3

// Four-step FFT: 16384 = 128x128. n = 128*n1 + n2, k = k1 + 128*k2.
//   step1: Y[k1][n2] = sum_n1 F[k1][n1] Z[n1][n2]
//   twiddle: Bm = Y * W_16384^(k1*n2)
//   step3: X[k1+128*k2] = sum_n2 Bm[k1][n2] F[n2][k2]  (F symmetric)
// LDS: SPLIT real/imag planes (raw b128 frag loads, no de-interleave VALU).
// Zt -> (reg panel) -> Bm overlay -> (reg panel) -> Ct interleaved overlay.

#define LDH 136              // halfs per plane row: 272B, 16B-aligned frag bases
#define PLN (128 * LDH)      // halfs per plane

typedef _Float16 h8 __attribute__((ext_vector_type(8)));
typedef float    f4 __attribute__((ext_vector_type(4)));

#define MFMA(a, b, c) __builtin_amdgcn_mfma_f32_16x16x32_f16((a), (b), (c), 0, 0, 0)

#define ANG128 (-0.04908738521234052f)    // -2pi/128
#define ANG16K (-3.834951969714103e-4f)   // -2pi/16384
#define ANG32K (-1.9174759848570515e-4f)  // -2pi/32768
#define GRC 0.9951847266721969f           // cos(2pi*512/32768)
#define GRS (-0.09801714032956060f)       // -sin(2pi*512/32768)

// MFMA fragment lane layout (gfx950 16x16x32, verified R8/R9 absmax=0):
//   A: lane l holds A[l&15][8*(l>>4)+j];  B: lane l holds B[8*(l>>4)+j][l&15]
//   D: lane l, reg v holds D[4*(l>>4)+v][l&15]

__device__ inline h8 ldf(const __half* p) {   // 16B-aligned ds_read_b128
    return *reinterpret_cast<const h8*>(p);
}

// |X[k]|^2 (ortho) from interleaved Ct[k2][k1]; twiddle (c,sn) given.
__device__ inline float bin_pow(const __half2* __restrict__ C, int k,
                                float c, float sn) {
    float2 a  = __half22float2(C[(k >> 7) * LDH + (k & 127)]);
    int p = MPTS - k;
    float2 bz = __half22float2(C[(p >> 7) * LDH + (p & 127)]);
    float bx = bz.x, by = -bz.y;                  // conj(Z[M-k])
    float ex = 0.5f * (a.x + bx), ey = 0.5f * (a.y + by);
    float dx = a.x - bx,          dy = a.y - by;
    float ox = 0.5f * dy,         oy = -0.5f * dx;
    float Xx = ex + ox * c - oy * sn;
    float Xy = ey + ox * sn + oy * c;
    return (Xx * Xx + Xy * Xy) * (1.0f / (float)NPTS);
}

__device__ inline float bin_pow_sc(const __half2* __restrict__ C, int k) {
    float c, sn;
    __sincosf(ANG32K * (float)k, &sn, &c);
    return bin_pow(C, k, c, sn);
}

// (512,4): VGPR cap 128 (4 waves/SIMD keeps two 8-wave blocks schedulable).
// Spill tripwires: FETCH_SIZE >> 66 MB or WRITE_SIZE >> 32 KB.
__global__ __launch_bounds__(NTHR, 4) void snr_row_kernel(
        const float* __restrict__ outs,
        const float* __restrict__ targets,
        float* __restrict__ row_loss) {
    __shared__ __align__(16) __half pl[2 * PLN];  // [plane][128][LDH], 68 KiB
    __shared__ float red[NTHR / 64];

    const int b    = blockIdx.x;
    const int tid  = threadIdx.x;
    const int lane = tid & 63;
    const int w    = tid >> 6;          // wave id 0..7 = panel id
    const int r15  = lane & 15;
    const int g    = lane >> 4;         // 0..3
    const float2* row = reinterpret_cast<const float2*>(outs + (size_t)b * NPTS);

    // ---- Stage: Zt[n2][n1], split planes (coalesced global b64 reads)
    #pragma unroll
    for (int it = 0; it < MPTS / NTHR; ++it) {
        int m = tid + it * NTHR;
        float2 v = row[m];
        int idx = (m & 127) * LDH + (m >> 7);
        pl[idx]       = (__half)v.x;
        pl[PLN + idx] = (__half)v.y;
    }

    // ---- F fragments: F[16w+r15][32kc+8g+j], recurrence (5 sincos total).
    h8 fr[4], fi[4];
    {
        const int frow = 16 * w + r15;
        float stc, sts;
        __sincosf(ANG128 * (float)frow, &sts, &stc);    // step e^{-2pi i row/128}
        #pragma unroll
        for (int kc = 0; kc < 4; ++kc) {
            int e0 = (frow * (32 * kc + 8 * g)) & 127;  // exact start
            float c, s;
            __sincosf(ANG128 * (float)e0, &s, &c);
            #pragma unroll
            for (int j = 0; j < 8; ++j) {
                fr[kc][j] = (_Float16)c;
                fi[kc][j] = (_Float16)s;
                float nc = c * stc - s * sts;
                s = c * sts + s * stc;
                c = nc;
            }
        }
    }
    __syncthreads();

    // ---- Twiddle recurrence state: per v, angle(n0) = -2pi k1(16 n0+r15)/16384
    float tc[4], ts[4], uc[4], us[4];
    #pragma unroll
    for (int v = 0; v < 4; ++v) {
        int k1 = 16 * w + 4 * g + v;
        __sincosf(ANG16K * (float)(k1 * r15), &ts[v], &tc[v]);   // n0=0 (exact)
        __sincosf(ANG16K * (float)(16 * k1), &us[v], &uc[v]);    // step
    }

    // ---- Step 1: Y(panel w) = F * Z; twiddle; pack panel into registers.
    __half2 bm[8][4];                   // statically indexed after unroll
    #pragma unroll
    for (int n0 = 0; n0 < 8; ++n0) {
        f4 accr = {0.f, 0.f, 0.f, 0.f}, acci = {0.f, 0.f, 0.f, 0.f};
        #pragma unroll
        for (int kc = 0; kc < 4; ++kc) {
            int base = (16 * n0 + r15) * LDH + 32 * kc + 8 * g;
            h8 zr = ldf(&pl[base]);
            h8 zi = ldf(&pl[PLN + base]);
            h8 fin = -fi[kc];
            accr = MFMA(fr[kc], zr, accr);      // Yr = Fr Zr - Fi Zi
            accr = MFMA(fin,    zi, accr);
            acci = MFMA(fr[kc], zi, acci);      // Yi = Fr Zi + Fi Zr
            acci = MFMA(fi[kc], zr, acci);
        }
        #pragma unroll
        for (int v = 0; v < 4; ++v) {
            float br = accr[v] * tc[v] - acci[v] * ts[v];
            float bi = accr[v] * ts[v] + acci[v] * tc[v];
            bm[n0][v] = __floats2half2_rn(br, bi);
            float nc = tc[v] * uc[v] - ts[v] * us[v];   // rotate to next n0
            ts[v] = tc[v] * us[v] + ts[v] * uc[v];
            tc[v] = nc;
        }
    }
    __syncthreads();    // all Zt reads complete

    // ---- Overlay-write Bm[k1][n2] into split planes (wave-owned rows)
    #pragma unroll
    for (int n0 = 0; n0 < 8; ++n0)
        #pragma unroll
        for (int v = 0; v < 4; ++v) {
            int idx = (16 * w + 4 * g + v) * LDH + 16 * n0 + r15;
            pl[idx]       = __low2half(bm[n0][v]);
            pl[PLN + idx] = __high2half(bm[n0][v]);
        }
    __syncthreads();

    // ---- Step 3: X = Bm * F (col panel w); pack panel into registers.
    __half2 ct[8][4];
    #pragma unroll
    for (int m0 = 0; m0 < 8; ++m0) {
        f4 accr = {0.f, 0.f, 0.f, 0.f}, acci = {0.f, 0.f, 0.f, 0.f};
        #pragma unroll
        for (int kc = 0; kc < 4; ++kc) {
            int base = (16 * m0 + r15) * LDH + 32 * kc + 8 * g;
            h8 ar = ldf(&pl[base]);
            h8 ai = ldf(&pl[PLN + base]);
            h8 ain = -ai;
            accr = MFMA(ar,  fr[kc], accr);     // Xr = Br Fr - Bi Fi
            accr = MFMA(ain, fi[kc], accr);
            acci = MFMA(ar,  fi[kc], acci);     // Xi = Br Fi + Bi Fr
            acci = MFMA(ai,  fr[kc], acci);
        }
        #pragma unroll
        for (int v = 0; v < 4; ++v)
            ct[m0][v] = __floats2half2_rn(accr[v], acci[v]);
    }
    __syncthreads();    // all Bm reads complete

    // ---- Overlay-write interleaved Ct[k2][k1] across BOTH planes (exactly
    // fills them: 128*LDH half2 == 2 planes of halfs).
    __half2* C = reinterpret_cast<__half2*>(pl);
    #pragma unroll
    for (int m0 = 0; m0 < 8; ++m0)
        #pragma unroll
        for (int v = 0; v < 4; ++v)
            C[(16 * w + r15) * LDH + 16 * m0 + 4 * g + v] = ct[m0][v];
    __syncthreads();

    // ---- Band power sum [MIN_IDX, MAX_IDX): direct indexing, coalesced;
    // untangle twiddle by recurrence (1 sincos + rotate by e^{-2pi i/64}).
    float local = 0.0f;
    {
        int k = MIN_IDX + tid;
        float cc, ss;
        __sincosf(ANG32K * (float)k, &ss, &cc);
        for (; k < MAX_IDX; k += NTHR) {
            local += bin_pow(C, k, cc, ss);
            float nc = cc * GRC - ss * GRS;
            ss = cc * GRS + ss * GRC;
            cc = nc;
        }
    }
    for (int off = 32; off; off >>= 1) local += __shfl_down(local, off);
    if ((tid & 63) == 0) red[w] = local;
    __syncthreads();

    if (tid == 0) {
        float S = 0.0f;
        #pragma unroll
        for (int q = 0; q < NTHR / 64; ++q) S += red[q];

        // ref_idx: argmin_k |f[k]-t|, f[k] = k*(10/16384) exact in fp32.
        float tgt = targets[b];
        double kd = (double)tgt * (16384.0 / 10.0);
        int k0 = (int)kd;                       // t>0 so trunc == floor
        const float stepf = 10.0f / 16384.0f;   // exactly representable
        float f0 = (float)k0 * stepf;           // exact products (<=24b)
        float f1 = (float)(k0 + 1) * stepf;
        float d0 = fabsf(f0 - tgt);
        float d1 = fabsf(f1 - tgt);
        int rr = (d0 <= d1) ? k0 : (k0 + 1);

        float pm1 = bin_pow_sc(C, rr - 1);
        float p0  = bin_pow_sc(C, rr);
        float pp1 = bin_pow_sc(C, rr + 1);
        float other_avg = (S - pm1 - p0 - pp1) * (1.0f / DENOMF);
        row_loss[b] = -10.0f * log10f(p0 / other_avg);
    }
}

__global__ __launch_bounds__(256) void snr_reduce_kernel(
        const float* __restrict__ row_loss, float* __restrict__ out) {
    __shared__ float red[4];
    float s = 0.0f;
    for (int i = threadIdx.x; i < BROWS; i += 256) s += row_loss[i];
    for (int off = 32; off; off >>= 1) s += __shfl_down(s, off);
    if ((threadIdx.x & 63) == 0) red[threadIdx.x >> 6] = s;
    __syncthreads();
    if (threadIdx.x == 0)
        out[0] = (red[0] + red[1] + red[2] + red[3]) * (1.0f / (float)BROWS);
}

extern "C" void kernel_launch(void* const* d_in, const int* in_sizes, int n_in,
                              void* d_out, int out_size, void* d_ws, size_t ws_size,
                              hipStream_t stream) {
    const float* outs    = (const float*)d_in[0];
    const float* targets = (const float*)d_in[1];
    float* ws  = (float*)d_ws;    // 1024 per-row losses
    float* out = (float*)d_out;

    snr_row_kernel<<<BROWS, NTHR, 0, stream>>>(outs, targets, ws);
    snr_reduce_kernel<<<1, 256, 0, stream>>>(ws, out);
}